// Round 9
// baseline (286.486 us; speedup 1.0000x reference)
//
#include <hip/hip_runtime.h>
#include <math.h>

// MoE: T=4096, D=1024, H=2048, O=1024, E=8, top-2.
// Routed sparse: 68.7 GFLOP bf16 MFMA. GEMMs: m97-proven geometry —
// 128x128 tile, BK=32, 4 waves (64x64/wave), 32 KB LDS dbuf, ~3 blocks/CU
// (launch_bounds(256,3)). Flat-slot row tiling (exactly 64 tiles of 128),
// expert-boundary tiles dual-pass. rt-major bid mapping so concurrent blocks
// share the A-tile (round-6's nt-major mapping caused 190 MB FETCH).

#define T_TOK 4096
#define DIM   1024
#define HID   2048
#define OUTD  1024
#define NE    8

typedef __bf16 bf16_t;
typedef __bf16 bf16x8 __attribute__((ext_vector_type(8)));
typedef float  f32x4  __attribute__((ext_vector_type(4)));

typedef __attribute__((address_space(3))) void       as3_void;
typedef __attribute__((address_space(1))) const void as1_void;
#define GLDS16(src, dst) \
  __builtin_amdgcn_global_load_lds((as1_void*)(src), (as3_void*)(dst), 16, 0, 0)

// ------- gating: logits (fp32 lane-partials, fp64 reduce), top-2, x->bf16 ---
__global__ void k_gate(const float* __restrict__ x, const float* __restrict__ Wg,
                       const float* __restrict__ bg, int* __restrict__ einfo,
                       float2* __restrict__ gpair, bf16_t* __restrict__ xb) {
  int wid  = threadIdx.x >> 6;
  int lane = threadIdx.x & 63;
  int t = blockIdx.x * 4 + wid;

  const float4* xr = (const float4*)(x + (size_t)t * DIM);
  float4 xv4[4];
  float sf[NE];
#pragma unroll
  for (int e = 0; e < NE; ++e) sf[e] = 0.f;

#pragma unroll
  for (int i = 0; i < 4; ++i) {
    int q = lane + 64 * i;
    float4 xv = xr[q];
    xv4[i] = xv;
    int d = q * 4;
#pragma unroll
    for (int c = 0; c < 4; ++c) {
      float xc = (&xv.x)[c];
      const float4* wr = (const float4*)(Wg + (size_t)(d + c) * NE);
      float4 w0 = wr[0], w1 = wr[1];
      sf[0] += xc * w0.x; sf[1] += xc * w0.y;
      sf[2] += xc * w0.z; sf[3] += xc * w0.w;
      sf[4] += xc * w1.x; sf[5] += xc * w1.y;
      sf[6] += xc * w1.z; sf[7] += xc * w1.w;
    }
  }

  ushort4* xbr = (ushort4*)(xb + (size_t)t * DIM);
#pragma unroll
  for (int i = 0; i < 4; ++i) {
    union { bf16_t b[4]; ushort4 u; } cv;
    cv.b[0] = (bf16_t)xv4[i].x; cv.b[1] = (bf16_t)xv4[i].y;
    cv.b[2] = (bf16_t)xv4[i].z; cv.b[3] = (bf16_t)xv4[i].w;
    xbr[lane + 64 * i] = cv.u;
  }

  double s[NE];
#pragma unroll
  for (int e = 0; e < NE; ++e) s[e] = (double)sf[e];
#pragma unroll
  for (int off = 32; off > 0; off >>= 1) {
#pragma unroll
    for (int e = 0; e < NE; ++e) s[e] += __shfl_xor(s[e], off);
  }

  if (lane == 0) {
    double v0 = -1e300, v1 = -1e300;
    int i0 = 0, i1 = 0;
#pragma unroll
    for (int e = 0; e < NE; ++e) {
      double v = s[e] + (double)bg[e];
      if (v > v0)      { v1 = v0; i1 = i0; v0 = v; i0 = e; }
      else if (v > v1) { v1 = v;  i1 = e; }
    }
    float ex = expf((float)(v1 - v0));
    float inv = 1.0f / (1.0f + ex);
    einfo[t] = i0 | (i1 << 8);
    gpair[t] = make_float2(inv, ex * inv);
  }
}

// ------- binning: ballot stream-compaction, wave w = expert w ---------------
// Also emits flat token list ftok[slot] for gemm1's gathered A-staging.
__global__ void k_bin(const int* __restrict__ einfo, const float2* __restrict__ gpair,
                      int* __restrict__ cnt, int* __restrict__ offs,
                      int* __restrict__ elist, float* __restrict__ egate,
                      int* __restrict__ tokrec, int* __restrict__ ftok) {
  __shared__ int scnt[NE];
  int w = threadIdx.x >> 6;
  int lane = threadIdx.x & 63;
  unsigned long long below = (lane == 0) ? 0ull : ((~0ull) >> (64 - lane));
  int base = 0;
  for (int c = 0; c < T_TOK / 64; ++c) {
    int t = c * 64 + lane;
    int ei = einfo[t];
    float2 g = gpair[t];
    int e0 = ei & 0xff, e1 = ei >> 8;
    bool m0 = (e0 == w);
    bool m  = m0 || (e1 == w);
    unsigned long long mask = __ballot(m);
    if (m) {
      int pos = base + (int)__popcll(mask & below);
      elist[w * T_TOK + pos] = t;
      egate[w * T_TOK + pos] = m0 ? g.x : g.y;
      tokrec[2 * t + (m0 ? 0 : 1)] = (w << 16) | pos;
    }
    base += (int)__popcll(mask);
  }
  if (lane == 0) scnt[w] = base;
  __syncthreads();
  if (threadIdx.x == 0) {
    int a = 0;
#pragma unroll
    for (int e = 0; e < NE; ++e) {
      cnt[e] = scnt[e];
      offs[e] = a;
      a += scnt[e];
    }
    offs[NE] = a;
  }
  // flat token list
  int off_w = 0;
#pragma unroll
  for (int i = 0; i < NE; ++i)
    if (i < w) off_w += scnt[i];
  int n_w = scnt[w];
  for (int p = lane; p < n_w; p += 64)
    ftok[off_w + p] = elist[w * T_TOK + p];
}

// ------------- per-expert transpose + convert: W[R][C] -> Wt[C][R] bf16 -----
__global__ void k_tr(const float* __restrict__ W, bf16_t* __restrict__ Wt,
                     int R, int C) {
  __shared__ float tile[32][33];
  size_t ebase = (size_t)blockIdx.z * R * C;
  int c0 = blockIdx.x * 32, r0 = blockIdx.y * 32;
  int id = threadIdx.x;
  int rc = id >> 5, cc = id & 31;
#pragma unroll
  for (int i = 0; i < 4; ++i)
    tile[rc + i * 8][cc] = W[ebase + (size_t)(r0 + rc + i * 8) * C + c0 + cc];
  __syncthreads();
  int oc = id >> 4, orp = id & 15;
  ushort2* wt2 = (ushort2*)(Wt + ebase);
#pragma unroll
  for (int i = 0; i < 2; ++i) {
    int c = oc + i * 16;
    union { bf16_t b[2]; ushort2 u; } cv;
    cv.b[0] = (bf16_t)tile[orp * 2][c];
    cv.b[1] = (bf16_t)tile[orp * 2 + 1][c];
    wt2[((size_t)(c0 + c) * R + r0 + orp * 2) >> 1] = cv.u;
  }
}

// Swizzle (BK=32, row = 64 B = 4 chunks): chunk' = chunk ^ ((row>>1)&3).
// ds_read_b128 at fixed lh: even rows 2-way, odd rows 2-way -> conflict-free.

// ---------------- GEMM1: h = relu(gather(x) @ W1 + b1) ----------------------
// 128x128, BK=32, 4 waves (2x2, 64x64/wave). Grid 64 rt x 16 nt, rt-major.
__launch_bounds__(256, 3)
__global__ void k_gemm1(const bf16_t* __restrict__ xb, const bf16_t* __restrict__ W1t,
                        const float* __restrict__ b1, const int* __restrict__ offs,
                        const int* __restrict__ ftok, bf16_t* __restrict__ hbuf) {
  const int bid = blockIdx.x;
  const int nt = bid & 15, rt = bid >> 4;   // consecutive bids share rt (A-tile)
  const int r0 = rt * 128;

  __shared__ __align__(16) char smem[32768];  // A: 2x8KB @0, B: 2x8KB @16384

  const int tid = threadIdx.x, lane = tid & 63, wid = tid >> 6;
  const int wm = wid >> 1, wn = wid & 1;
  const int fr = lane & 15, lh = lane >> 4;

  // staging: thread covers chunks tid (row tid>>2) and tid+256 (row 64+..)
  const int ar0 = tid >> 2, sk0 = (tid & 3) ^ ((ar0 >> 1) & 3);
  const int ar1 = 64 + ar0, sk1 = (tid & 3) ^ ((ar1 >> 1) & 3);
  const char* srcA0 = (const char*)xb + ((size_t)ftok[r0 + ar0] * DIM + sk0 * 8) * 2;
  const char* srcA1 = (const char*)xb + ((size_t)ftok[r0 + ar1] * DIM + sk1 * 8) * 2;

  unsigned rdA[4], rdB[4];
#pragma unroll
  for (int mi = 0; mi < 4; ++mi) {
    int r = wm * 64 + mi * 16 + fr;
    rdA[mi] = (unsigned)(r * 64 + ((lh ^ ((r >> 1) & 3)) * 16));
  }
#pragma unroll
  for (int nj = 0; nj < 4; ++nj) {
    int r = wn * 64 + nj * 16 + fr;
    rdB[nj] = (unsigned)(r * 64 + ((lh ^ ((r >> 1) & 3)) * 16));
  }

  const int NT = DIM / 32;  // 32

  int e = 0;
  while (offs[e + 1] <= r0) ++e;
  for (;;) {
    const int lo = offs[e] > r0 ? offs[e] : r0;
    const int hi = offs[e + 1] < r0 + 128 ? offs[e + 1] : r0 + 128;

    if (hi > lo) {
      const char* srcB0 = (const char*)W1t +
          ((size_t)(e * HID + nt * 128 + ar0) * DIM + sk0 * 8) * 2;
      const char* srcB1 = (const char*)W1t +
          ((size_t)(e * HID + nt * 128 + ar1) * DIM + sk1 * 8) * 2;

      f32x4 acc[4][4];
#pragma unroll
      for (int i = 0; i < 4; ++i)
#pragma unroll
        for (int j = 0; j < 4; ++j) acc[i][j] = (f32x4){0.f, 0.f, 0.f, 0.f};

      GLDS16(srcA0, smem + tid * 16);
      GLDS16(srcA1, smem + (256 + tid) * 16);
      GLDS16(srcB0, smem + 16384 + tid * 16);
      GLDS16(srcB1, smem + 16384 + (256 + tid) * 16);

#pragma unroll 2
      for (int t = 0; t < NT; ++t) {
        if (t + 1 < NT) {
          char* da = smem + ((t + 1) & 1) * 8192;
          char* db = smem + 16384 + ((t + 1) & 1) * 8192;
          GLDS16(srcA0 + (t + 1) * 64, da + tid * 16);
          GLDS16(srcA1 + (t + 1) * 64, da + (256 + tid) * 16);
          GLDS16(srcB0 + (t + 1) * 64, db + tid * 16);
          GLDS16(srcB1 + (t + 1) * 64, db + (256 + tid) * 16);
        }
        __syncthreads();
        const char* a_ = smem + (t & 1) * 8192;
        const char* b_ = smem + 16384 + (t & 1) * 8192;
        bf16x8 af[4], bfv[4];
#pragma unroll
        for (int mi = 0; mi < 4; ++mi) af[mi] = *(const bf16x8*)(a_ + rdA[mi]);
#pragma unroll
        for (int nj = 0; nj < 4; ++nj) bfv[nj] = *(const bf16x8*)(b_ + rdB[nj]);
#pragma unroll
        for (int mi = 0; mi < 4; ++mi)
#pragma unroll
          for (int nj = 0; nj < 4; ++nj)
            acc[mi][nj] = __builtin_amdgcn_mfma_f32_16x16x32_bf16(
                af[mi], bfv[nj], acc[mi][nj], 0, 0, 0);
        __syncthreads();
      }

#pragma unroll
      for (int mi = 0; mi < 4; ++mi) {
#pragma unroll
        for (int rr = 0; rr < 4; ++rr) {
          int row = r0 + wm * 64 + mi * 16 + lh * 4 + rr;
          if (row >= lo && row < hi) {
            size_t hrow = (size_t)row * HID;
#pragma unroll
            for (int nj = 0; nj < 4; ++nj) {
              int col = nt * 128 + wn * 64 + nj * 16 + fr;
              float v = acc[mi][nj][rr] + b1[e * HID + col];
              hbuf[hrow + col] = (bf16_t)(v > 0.f ? v : 0.f);
            }
          }
        }
      }
    }

    if (offs[e + 1] >= r0 + 128) break;
    ++e;
  }
}

// ---------------- GEMM2: y[slot] = gate * (h @ W2 + b2) ---------------------
// 128x128, BK=32, 4 waves. Grid 64 rt x 8 nt, rt-major. K=2048 -> 64 steps.
__launch_bounds__(256, 3)
__global__ void k_gemm2(const bf16_t* __restrict__ hbuf, const bf16_t* __restrict__ W2t,
                        const float* __restrict__ b2, const int* __restrict__ offs,
                        const float* __restrict__ egate, float* __restrict__ y) {
  const int bid = blockIdx.x;
  const int nt = bid & 7, rt = bid >> 3;
  const int r0 = rt * 128;

  __shared__ __align__(16) char smem[32768];

  const int tid = threadIdx.x, lane = tid & 63, wid = tid >> 6;
  const int wm = wid >> 1, wn = wid & 1;
  const int fr = lane & 15, lh = lane >> 4;

  const int ar0 = tid >> 2, sk0 = (tid & 3) ^ ((ar0 >> 1) & 3);
  const int ar1 = 64 + ar0, sk1 = (tid & 3) ^ ((ar1 >> 1) & 3);
  const char* srcA0 = (const char*)hbuf + ((size_t)(r0 + ar0) * HID + sk0 * 8) * 2;
  const char* srcA1 = (const char*)hbuf + ((size_t)(r0 + ar1) * HID + sk1 * 8) * 2;

  unsigned rdA[4], rdB[4];
#pragma unroll
  for (int mi = 0; mi < 4; ++mi) {
    int r = wm * 64 + mi * 16 + fr;
    rdA[mi] = (unsigned)(r * 64 + ((lh ^ ((r >> 1) & 3)) * 16));
  }
#pragma unroll
  for (int nj = 0; nj < 4; ++nj) {
    int r = wn * 64 + nj * 16 + fr;
    rdB[nj] = (unsigned)(r * 64 + ((lh ^ ((r >> 1) & 3)) * 16));
  }

  const int NT = HID / 32;  // 64

  int e = 0;
  while (offs[e + 1] <= r0) ++e;
  for (;;) {
    const int lo = offs[e] > r0 ? offs[e] : r0;
    const int hi = offs[e + 1] < r0 + 128 ? offs[e + 1] : r0 + 128;

    if (hi > lo) {
      const char* srcB0 = (const char*)W2t +
          ((size_t)(e * OUTD + nt * 128 + ar0) * HID + sk0 * 8) * 2;
      const char* srcB1 = (const char*)W2t +
          ((size_t)(e * OUTD + nt * 128 + ar1) * HID + sk1 * 8) * 2;

      f32x4 acc[4][4];
#pragma unroll
      for (int i = 0; i < 4; ++i)
#pragma unroll
        for (int j = 0; j < 4; ++j) acc[i][j] = (f32x4){0.f, 0.f, 0.f, 0.f};

      GLDS16(srcA0, smem + tid * 16);
      GLDS16(srcA1, smem + (256 + tid) * 16);
      GLDS16(srcB0, smem + 16384 + tid * 16);
      GLDS16(srcB1, smem + 16384 + (256 + tid) * 16);

#pragma unroll 2
      for (int t = 0; t < NT; ++t) {
        if (t + 1 < NT) {
          char* da = smem + ((t + 1) & 1) * 8192;
          char* db = smem + 16384 + ((t + 1) & 1) * 8192;
          GLDS16(srcA0 + (t + 1) * 64, da + tid * 16);
          GLDS16(srcA1 + (t + 1) * 64, da + (256 + tid) * 16);
          GLDS16(srcB0 + (t + 1) * 64, db + tid * 16);
          GLDS16(srcB1 + (t + 1) * 64, db + (256 + tid) * 16);
        }
        __syncthreads();
        const char* a_ = smem + (t & 1) * 8192;
        const char* b_ = smem + 16384 + (t & 1) * 8192;
        bf16x8 af[4], bfv[4];
#pragma unroll
        for (int mi = 0; mi < 4; ++mi) af[mi] = *(const bf16x8*)(a_ + rdA[mi]);
#pragma unroll
        for (int nj = 0; nj < 4; ++nj) bfv[nj] = *(const bf16x8*)(b_ + rdB[nj]);
#pragma unroll
        for (int mi = 0; mi < 4; ++mi)
#pragma unroll
          for (int nj = 0; nj < 4; ++nj)
            acc[mi][nj] = __builtin_amdgcn_mfma_f32_16x16x32_bf16(
                af[mi], bfv[nj], acc[mi][nj], 0, 0, 0);
        __syncthreads();
      }

#pragma unroll
      for (int mi = 0; mi < 4; ++mi) {
#pragma unroll
        for (int rr = 0; rr < 4; ++rr) {
          int row = r0 + wm * 64 + mi * 16 + lh * 4 + rr;
          if (row >= lo && row < hi) {
            float gate = egate[e * T_TOK + row - offs[e]];
            size_t yrow = (size_t)row * OUTD;
#pragma unroll
            for (int nj = 0; nj < 4; ++nj) {
              int col = nt * 128 + wn * 64 + nj * 16 + fr;
              y[yrow + col] = gate * (acc[mi][nj][rr] + b2[e * OUTD + col]);
            }
          }
        }
      }
    }

    if (offs[e + 1] >= r0 + 128) break;
    ++e;
  }
}

// ---------------- combine: out[t] = y[slot0] + y[slot1] ---------------------
__global__ void k_combine(const float* __restrict__ y, const int* __restrict__ offs,
                          const int* __restrict__ tokrec, float* __restrict__ out) {
  int t = blockIdx.x;
  int r0 = tokrec[2 * t], r1 = tokrec[2 * t + 1];
  int s0 = offs[r0 >> 16] + (r0 & 0xffff);
  int s1 = offs[r1 >> 16] + (r1 & 0xffff);
  const float4* ya = (const float4*)(y + (size_t)s0 * OUTD);
  const float4* yb = (const float4*)(y + (size_t)s1 * OUTD);
  float4* o = (float4*)(out + (size_t)t * OUTD);
  int i = threadIdx.x;
  float4 a = ya[i], b = yb[i];
  o[i] = make_float4(a.x + b.x, a.y + b.y, a.z + b.z, a.w + b.w);
}

// ---------------------------------------------------------------------------
extern "C" void kernel_launch(void* const* d_in, const int* in_sizes, int n_in,
                              void* d_out, int out_size, void* d_ws, size_t ws_size,
                              hipStream_t stream) {
  const float* x  = (const float*)d_in[0];
  const float* Wg = (const float*)d_in[1];
  const float* bg = (const float*)d_in[2];
  const float* W1 = (const float*)d_in[3];
  const float* b1 = (const float*)d_in[4];
  const float* W2 = (const float*)d_in[5];
  const float* b2 = (const float*)d_in[6];
  float* out = (float*)d_out;

  char* ws = (char*)d_ws;
  int*    cnt    = (int*)(ws);
  int*    offs   = (int*)(ws + 1024);
  int*    tokrec = (int*)(ws + 4096);                       // 32 KB
  int*    einfo  = (int*)(ws + 36864);                      // 16 KB
  float2* gpair  = (float2*)(ws + 53248);                   // 32 KB
  int*    elist  = (int*)(ws + 131072);                     // 128 KB
  float*  egate  = (float*)(ws + 262144);                   // 128 KB
  int*    ftok   = (int*)(ws + 393216);                     // 32 KB
  bf16_t* W1t    = (bf16_t*)(ws + (1u << 20));              // 32 MB
  float*  y      = (float*)(ws + (1u << 20));               // aliases W1t (dead by gemm2)
  bf16_t* W2t    = (bf16_t*)(ws + (1u << 20) + (32u << 20));// 32 MB
  bf16_t* xb     = (bf16_t*)(ws + (1u << 20) + (64u << 20));// 8 MB
  bf16_t* hbuf   = (bf16_t*)(ws + (1u << 20) + (72u << 20));// 32 MB

  k_gate<<<T_TOK / 4, 256, 0, stream>>>(x, Wg, bg, einfo, gpair, xb);
  k_bin<<<1, 512, 0, stream>>>(einfo, gpair, cnt, offs, elist, egate, tokrec, ftok);
  k_tr<<<dim3(HID / 32, DIM / 32, NE), 256, 0, stream>>>(W1, W1t, DIM, HID);
  k_tr<<<dim3(OUTD / 32, HID / 32, NE), 256, 0, stream>>>(W2, W2t, HID, OUTD);

  k_gemm1<<<(T_TOK * 2 / 128) * (HID / 128), 256, 0, stream>>>(
      xb, W1t, b1, offs, ftok, hbuf);
  k_gemm2<<<(T_TOK * 2 / 128) * (OUTD / 128), 256, 0, stream>>>(
      hbuf, W2t, b2, offs, egate, y);
  k_combine<<<T_TOK, 256, 0, stream>>>(y, offs, tokrec, out);
}